// Round 1
// baseline (801.042 us; speedup 1.0000x reference)
//
#include <hip/hip_runtime.h>

typedef unsigned short u16;
typedef __attribute__((ext_vector_type(8))) short bf16x8;
typedef __attribute__((ext_vector_type(4))) float f32x4;

#define MFMA16(a,b,c) __builtin_amdgcn_mfma_f32_16x16x32_bf16((a),(b),(c),0,0,0)

static __device__ __forceinline__ u16 f2bf(float x){
    unsigned int u = __float_as_uint(x);
    u += 0x7FFFu + ((u >> 16) & 1u);
    return (u16)(u >> 16);
}

// B-fragment for mfma_f32_16x16x32_bf16 from a row-major [K][ldn] f32 weight.
// lane holds B[k0 .. k0+7][n]  (same k-slot mapping as our A-frags -> consistent)
static __device__ __forceinline__ bf16x8 load_bfrag(const float* __restrict__ W, int ldn, int n, int k0){
    bf16x8 r;
    #pragma unroll
    for (int j = 0; j < 8; ++j) r[j] = (short)f2bf(W[(k0 + j) * ldn + n]);
    return r;
}

// ---------------- encoder: h = relu(x@W1+b1)@W2 + b2  -> hbf [N][64] bf16 ----
__global__ __launch_bounds__(256) void enc_kernel(
    const float* __restrict__ X, const float* __restrict__ W1, const float* __restrict__ B1,
    const float* __restrict__ W2, const float* __restrict__ B2,
    u16* __restrict__ hbf, int N)
{
    __shared__ u16 sHid[64 * 136];   // 64 nodes x 128 (+8 pad) bf16
    const int tid = threadIdx.x;
    const int w = tid >> 6, l = tid & 63, l15 = l & 15, quad = l >> 4;

    bf16x8 bW[4][4];
    #pragma unroll
    for (int ks = 0; ks < 4; ++ks)
        #pragma unroll
        for (int f = 0; f < 4; ++f)
            bW[ks][f] = load_bfrag(W2, 64, f * 16 + l15, ks * 32 + quad * 8);
    float b2v[4];
    #pragma unroll
    for (int f = 0; f < 4; ++f) b2v[f] = B2[f * 16 + l15];

    const int nbase = blockIdx.x * 64 + w * 16;

    // hidden for this wave's 16 nodes: lane covers node (l>>2), k-range (l&3)*32..+31
    {
        int e = l >> 2;
        int node = nbase + e; if (node > N - 1) node = N - 1;
        float x0 = X[node * 3], x1 = X[node * 3 + 1], x2 = X[node * 3 + 2];
        int k0 = (l & 3) * 32;
        u16* dst = sHid + (w * 16 + e) * 136 + k0;
        #pragma unroll
        for (int j = 0; j < 32; ++j){
            int k = k0 + j;
            float hv = x0 * W1[k] + x1 * W1[128 + k] + x2 * W1[256 + k] + B1[k];
            dst[j] = f2bf(hv > 0.f ? hv : 0.f);
        }
    }
    // same wave wrote, same wave reads -> lgkmcnt handled by compiler, no barrier

    f32x4 acc[4];
    #pragma unroll
    for (int f = 0; f < 4; ++f){ acc[f][0]=b2v[f]; acc[f][1]=b2v[f]; acc[f][2]=b2v[f]; acc[f][3]=b2v[f]; }
    #pragma unroll
    for (int ks = 0; ks < 4; ++ks){
        bf16x8 a = *(const bf16x8*)&sHid[(w * 16 + l15) * 136 + ks * 32 + quad * 8];
        #pragma unroll
        for (int f = 0; f < 4; ++f) acc[f] = MFMA16(a, bW[ks][f], acc[f]);
    }
    #pragma unroll
    for (int r = 0; r < 4; ++r){
        int node = nbase + quad * 4 + r;
        if (node < N){
            #pragma unroll
            for (int f = 0; f < 4; ++f)
                hbf[node * 64 + f * 16 + l15] = f2bf(acc[f][r]);
        }
    }
}

// ---------------- message + scatter-add -------------------------------------
// msg = relu([h[r]|h[c]|ef] @ W1 + b1) @ W2 + b2 ;  agg[rows] += msg
__global__ __launch_bounds__(256) void msg_kernel(
    const u16* __restrict__ hbf, const int* __restrict__ rows, const int* __restrict__ cols,
    const float* __restrict__ EF,
    const float* __restrict__ W1, const float* __restrict__ B1,
    const float* __restrict__ W2, const float* __restrict__ B2,
    float* __restrict__ agg, int E, int ntiles)
{
    __shared__ u16 sHid[64 * 72];    // 4 waves x 16 rows, stride 72 bf16 (conflict-optimal)
    const int tid = threadIdx.x;
    const int w = tid >> 6, l = tid & 63, l15 = l & 15, quad = l >> 4;

    // weights in registers (loop-invariant across tiles)
    bf16x8 bW1a[2][4], bW1b[2][4], bW2[2][4];
    #pragma unroll
    for (int kk = 0; kk < 2; ++kk)
        #pragma unroll
        for (int f = 0; f < 4; ++f){
            int n = f * 16 + l15, k0 = kk * 32 + quad * 8;
            bW1a[kk][f] = load_bfrag(W1,           64, n, k0);   // rows 0..63   (h[rows] part)
            bW1b[kk][f] = load_bfrag(W1 + 64 * 64, 64, n, k0);   // rows 64..127 (h[cols] part)
            bW2 [kk][f] = load_bfrag(W2,           64, n, k0);
        }
    float bias1[4], wc0[4], wc1[4], bias2[4];
    #pragma unroll
    for (int f = 0; f < 4; ++f){
        int n = f * 16 + l15;
        bias1[f] = B1[n];
        wc0[f]   = W1[128 * 64 + n];   // ef[0] row
        wc1[f]   = W1[129 * 64 + n];   // ef[1] row
        bias2[f] = B2[n];
    }

    u16* myHid = sHid + (w * 16) * 72;

    for (int tile = blockIdx.x; tile < ntiles; tile += gridDim.x){
        const int ebase = tile * 64 + w * 16;

        // A-side gather (lane's A-row edge = ebase + l15)
        int ea = ebase + l15; if (ea >= E) ea = 0;
        int rn = rows[ea], cn = cols[ea];
        const u16* prow = hbf + rn * 64 + quad * 8;
        const u16* pcol = hbf + cn * 64 + quad * 8;
        bf16x8 aR0 = *(const bf16x8*)(prow);
        bf16x8 aR1 = *(const bf16x8*)(prow + 32);
        bf16x8 aC0 = *(const bf16x8*)(pcol);
        bf16x8 aC1 = *(const bf16x8*)(pcol + 32);

        // accumulator-row edges (C-layout rows quad*4+r)
        float e0v[4], e1v[4]; int nidx[4];
        #pragma unroll
        for (int r = 0; r < 4; ++r){
            int e = ebase + quad * 4 + r; if (e >= E) e = 0;
            e0v[r] = EF[e * 2]; e1v[r] = EF[e * 2 + 1];
            nidx[r] = rows[e];
        }

        f32x4 acc[4];
        #pragma unroll
        for (int f = 0; f < 4; ++f)
            #pragma unroll
            for (int r = 0; r < 4; ++r)
                acc[f][r] = bias1[f] + e0v[r] * wc0[f] + e1v[r] * wc1[f];

        #pragma unroll
        for (int f = 0; f < 4; ++f) acc[f] = MFMA16(aR0, bW1a[0][f], acc[f]);
        #pragma unroll
        for (int f = 0; f < 4; ++f) acc[f] = MFMA16(aR1, bW1a[1][f], acc[f]);
        #pragma unroll
        for (int f = 0; f < 4; ++f) acc[f] = MFMA16(aC0, bW1b[0][f], acc[f]);
        #pragma unroll
        for (int f = 0; f < 4; ++f) acc[f] = MFMA16(aC1, bW1b[1][f], acc[f]);

        // relu -> bf16 -> LDS handoff (C-layout -> A-layout)
        #pragma unroll
        for (int f = 0; f < 4; ++f)
            #pragma unroll
            for (int r = 0; r < 4; ++r){
                float v = acc[f][r] > 0.f ? acc[f][r] : 0.f;
                myHid[(quad * 4 + r) * 72 + f * 16 + l15] = f2bf(v);
            }

        f32x4 m[4];
        #pragma unroll
        for (int f = 0; f < 4; ++f){ m[f][0]=bias2[f]; m[f][1]=bias2[f]; m[f][2]=bias2[f]; m[f][3]=bias2[f]; }
        #pragma unroll
        for (int kk = 0; kk < 2; ++kk){
            bf16x8 a = *(const bf16x8*)&myHid[l15 * 72 + kk * 32 + quad * 8];
            #pragma unroll
            for (int f = 0; f < 4; ++f) m[f] = MFMA16(a, bW2[kk][f], m[f]);
        }

        // scatter-add
        #pragma unroll
        for (int r = 0; r < 4; ++r){
            int e = ebase + quad * 4 + r;
            if (e < E){
                float* dst = agg + (size_t)nidx[r] * 64;
                #pragma unroll
                for (int f = 0; f < 4; ++f)
                    atomicAdd(dst + f * 16 + l15, m[f][r]);
            }
        }
    }
}

// ---------------- update: h = relu(LN(agg + h@skipW + skipB)) ----------------
__global__ __launch_bounds__(256) void update_kernel(
    u16* __restrict__ hbf, const float* __restrict__ agg,
    const float* __restrict__ SW, const float* __restrict__ SB,
    const float* __restrict__ LG, const float* __restrict__ LB, int N)
{
    const int tid = threadIdx.x;
    const int w = tid >> 6, l = tid & 63, l15 = l & 15, quad = l >> 4;

    bf16x8 bW[2][4];
    #pragma unroll
    for (int kk = 0; kk < 2; ++kk)
        #pragma unroll
        for (int f = 0; f < 4; ++f)
            bW[kk][f] = load_bfrag(SW, 64, f * 16 + l15, kk * 32 + quad * 8);
    float sb[4], lg[4], lb[4];
    #pragma unroll
    for (int f = 0; f < 4; ++f){
        int n = f * 16 + l15;
        sb[f] = SB[n]; lg[f] = LG[n]; lb[f] = LB[n];
    }

    const int nbase = blockIdx.x * 64 + w * 16;
    int na = nbase + l15; if (na > N - 1) na = N - 1;
    const u16* pa = hbf + (size_t)na * 64 + quad * 8;
    bf16x8 a0 = *(const bf16x8*)pa;
    bf16x8 a1 = *(const bf16x8*)(pa + 32);

    f32x4 acc[4] = {};
    #pragma unroll
    for (int f = 0; f < 4; ++f) acc[f] = MFMA16(a0, bW[0][f], acc[f]);
    #pragma unroll
    for (int f = 0; f < 4; ++f) acc[f] = MFMA16(a1, bW[1][f], acc[f]);

    float vals[4][4];
    #pragma unroll
    for (int r = 0; r < 4; ++r){
        int node = nbase + quad * 4 + r; if (node > N - 1) node = N - 1;
        #pragma unroll
        for (int f = 0; f < 4; ++f)
            vals[f][r] = acc[f][r] + sb[f] + agg[(size_t)node * 64 + f * 16 + l15];
    }

    #pragma unroll
    for (int r = 0; r < 4; ++r){
        float s  = vals[0][r] + vals[1][r] + vals[2][r] + vals[3][r];
        float sq = vals[0][r]*vals[0][r] + vals[1][r]*vals[1][r]
                 + vals[2][r]*vals[2][r] + vals[3][r]*vals[3][r];
        #pragma unroll
        for (int msk = 1; msk < 16; msk <<= 1){
            s  += __shfl_xor(s,  msk);
            sq += __shfl_xor(sq, msk);
        }
        float mean = s * (1.f / 64.f);
        float var  = sq * (1.f / 64.f) - mean * mean;
        float rstd = rsqrtf(var + 1e-5f);
        int node = nbase + quad * 4 + r;
        if (node < N){
            #pragma unroll
            for (int f = 0; f < 4; ++f){
                float hv = (vals[f][r] - mean) * rstd * lg[f] + lb[f];
                hv = hv > 0.f ? hv : 0.f;
                hbf[(size_t)node * 64 + f * 16 + l15] = f2bf(hv);
            }
        }
    }
}

// ---------------- head: out = relu(h@W1+b1)@W2 + b2  [N][8] f32 --------------
__global__ __launch_bounds__(256) void head_kernel(
    const u16* __restrict__ hbf,
    const float* __restrict__ W1, const float* __restrict__ B1,
    const float* __restrict__ W2, const float* __restrict__ B2,
    float* __restrict__ out, int N)
{
    __shared__ u16 sT[64 * 72];
    const int tid = threadIdx.x;
    const int w = tid >> 6, l = tid & 63, l15 = l & 15, quad = l >> 4;

    bf16x8 bW1[2][4];
    #pragma unroll
    for (int kk = 0; kk < 2; ++kk)
        #pragma unroll
        for (int f = 0; f < 4; ++f)
            bW1[kk][f] = load_bfrag(W1, 64, f * 16 + l15, kk * 32 + quad * 8);
    float b1v[4];
    #pragma unroll
    for (int f = 0; f < 4; ++f) b1v[f] = B1[f * 16 + l15];

    bf16x8 bW2[2];
    #pragma unroll
    for (int kk = 0; kk < 2; ++kk)
        #pragma unroll
        for (int j = 0; j < 8; ++j){
            int k = kk * 32 + quad * 8 + j;
            bW2[kk][j] = (l15 < 8) ? (short)f2bf(W2[k * 8 + l15]) : (short)0;
        }
    float b2v = (l15 < 8) ? B2[l15] : 0.f;

    const int nbase = blockIdx.x * 64 + w * 16;
    int na = nbase + l15; if (na > N - 1) na = N - 1;
    const u16* pa = hbf + (size_t)na * 64 + quad * 8;
    bf16x8 a0 = *(const bf16x8*)pa;
    bf16x8 a1 = *(const bf16x8*)(pa + 32);

    f32x4 acc[4];
    #pragma unroll
    for (int f = 0; f < 4; ++f){ acc[f][0]=b1v[f]; acc[f][1]=b1v[f]; acc[f][2]=b1v[f]; acc[f][3]=b1v[f]; }
    #pragma unroll
    for (int f = 0; f < 4; ++f) acc[f] = MFMA16(a0, bW1[0][f], acc[f]);
    #pragma unroll
    for (int f = 0; f < 4; ++f) acc[f] = MFMA16(a1, bW1[1][f], acc[f]);

    u16* myT = sT + (w * 16) * 72;
    #pragma unroll
    for (int f = 0; f < 4; ++f)
        #pragma unroll
        for (int r = 0; r < 4; ++r){
            float v = acc[f][r] > 0.f ? acc[f][r] : 0.f;
            myT[(quad * 4 + r) * 72 + f * 16 + l15] = f2bf(v);
        }

    f32x4 o = { b2v, b2v, b2v, b2v };
    #pragma unroll
    for (int kk = 0; kk < 2; ++kk){
        bf16x8 a = *(const bf16x8*)&myT[l15 * 72 + kk * 32 + quad * 8];
        o = MFMA16(a, bW2[kk], o);
    }
    #pragma unroll
    for (int r = 0; r < 4; ++r){
        int node = nbase + quad * 4 + r;
        if (node < N && l15 < 8)
            out[(size_t)node * 8 + l15] = o[r];
    }
}

extern "C" void kernel_launch(void* const* d_in, const int* in_sizes, int n_in,
                              void* d_out, int out_size, void* d_ws, size_t ws_size,
                              hipStream_t stream)
{
    const float* X      = (const float*)d_in[0];
    const int*   EI     = (const int*)d_in[1];
    const float* EF     = (const float*)d_in[2];
    const float* encW1  = (const float*)d_in[4];
    const float* encB1  = (const float*)d_in[5];
    const float* encW2  = (const float*)d_in[6];
    const float* encB2  = (const float*)d_in[7];
    const float* convW1 = (const float*)d_in[8];
    const float* convB1 = (const float*)d_in[9];
    const float* convW2 = (const float*)d_in[10];
    const float* convB2 = (const float*)d_in[11];
    const float* skipW  = (const float*)d_in[12];
    const float* skipB  = (const float*)d_in[13];
    const float* lnG    = (const float*)d_in[14];
    const float* lnB    = (const float*)d_in[15];
    const float* headW1 = (const float*)d_in[16];
    const float* headB1 = (const float*)d_in[17];
    const float* headW2 = (const float*)d_in[18];
    const float* headB2 = (const float*)d_in[19];

    const int N = in_sizes[0] / 3;
    const int E = in_sizes[1] / 2;
    const int L = in_sizes[8] / (130 * 64);
    const int* rows = EI;
    const int* cols = EI + E;

    u16*   hbf = (u16*)d_ws;
    size_t hbf_bytes = (((size_t)N * 64 * sizeof(u16)) + 255) & ~(size_t)255;
    float* agg = (float*)((char*)d_ws + hbf_bytes);

    const int ntilesN = (N + 63) / 64;
    const int ntilesE = (E + 63) / 64;
    const int msg_blocks = ntilesE < 1024 ? ntilesE : 1024;

    enc_kernel<<<ntilesN, 256, 0, stream>>>(X, encW1, encB1, encW2, encB2, hbf, N);
    for (int li = 0; li < L; ++li){
        hipMemsetAsync(agg, 0, (size_t)N * 64 * sizeof(float), stream);
        msg_kernel<<<msg_blocks, 256, 0, stream>>>(hbf, rows, cols, EF,
            convW1 + (size_t)li * 130 * 64, convB1 + li * 64,
            convW2 + (size_t)li * 64 * 64, convB2 + li * 64,
            agg, E, ntilesE);
        update_kernel<<<ntilesN, 256, 0, stream>>>(hbf, agg,
            skipW + (size_t)li * 64 * 64, skipB + li * 64,
            lnG + li * 64, lnB + li * 64, N);
    }
    head_kernel<<<ntilesN, 256, 0, stream>>>(hbf, headW1, headB1, headW2, headB2,
                                             (float*)d_out, N);
}

// Round 2
// 626.430 us; speedup vs baseline: 1.2787x; 1.2787x over previous
//
#include <hip/hip_runtime.h>

typedef unsigned short u16;
typedef __attribute__((ext_vector_type(8))) short bf16x8;
typedef __attribute__((ext_vector_type(4))) float f32x4;

#define MFMA16(a,b,c) __builtin_amdgcn_mfma_f32_16x16x32_bf16((a),(b),(c),0,0,0)

static __device__ __forceinline__ u16 f2bf(float x){
    unsigned int u = __float_as_uint(x);
    u += 0x7FFFu + ((u >> 16) & 1u);
    return (u16)(u >> 16);
}

static __device__ __forceinline__ bf16x8 load_bfrag(const float* __restrict__ W, int ldn, int n, int k0){
    bf16x8 r;
    #pragma unroll
    for (int j = 0; j < 8; ++j) r[j] = (short)f2bf(W[(k0 + j) * ldn + n]);
    return r;
}

// ---------------- encoder: h = relu(x@W1+b1)@W2 + b2  -> hbf [N][64] bf16 ----
__global__ __launch_bounds__(256) void enc_kernel(
    const float* __restrict__ X, const float* __restrict__ W1, const float* __restrict__ B1,
    const float* __restrict__ W2, const float* __restrict__ B2,
    u16* __restrict__ hbf, int N)
{
    __shared__ u16 sHid[64 * 136];
    const int tid = threadIdx.x;
    const int w = tid >> 6, l = tid & 63, l15 = l & 15, quad = l >> 4;

    bf16x8 bW[4][4];
    #pragma unroll
    for (int ks = 0; ks < 4; ++ks)
        #pragma unroll
        for (int f = 0; f < 4; ++f)
            bW[ks][f] = load_bfrag(W2, 64, f * 16 + l15, ks * 32 + quad * 8);
    float b2v[4];
    #pragma unroll
    for (int f = 0; f < 4; ++f) b2v[f] = B2[f * 16 + l15];

    const int nbase = blockIdx.x * 64 + w * 16;

    {
        int e = l >> 2;
        int node = nbase + e; if (node > N - 1) node = N - 1;
        float x0 = X[node * 3], x1 = X[node * 3 + 1], x2 = X[node * 3 + 2];
        int k0 = (l & 3) * 32;
        u16* dst = sHid + (w * 16 + e) * 136 + k0;
        #pragma unroll
        for (int j = 0; j < 32; ++j){
            int k = k0 + j;
            float hv = x0 * W1[k] + x1 * W1[128 + k] + x2 * W1[256 + k] + B1[k];
            dst[j] = f2bf(hv > 0.f ? hv : 0.f);
        }
    }

    f32x4 acc[4];
    #pragma unroll
    for (int f = 0; f < 4; ++f){ acc[f][0]=b2v[f]; acc[f][1]=b2v[f]; acc[f][2]=b2v[f]; acc[f][3]=b2v[f]; }
    #pragma unroll
    for (int ks = 0; ks < 4; ++ks){
        bf16x8 a = *(const bf16x8*)&sHid[(w * 16 + l15) * 136 + ks * 32 + quad * 8];
        #pragma unroll
        for (int f = 0; f < 4; ++f) acc[f] = MFMA16(a, bW[ks][f], acc[f]);
    }
    #pragma unroll
    for (int r = 0; r < 4; ++r){
        int node = nbase + quad * 4 + r;
        if (node < N){
            #pragma unroll
            for (int f = 0; f < 4; ++f)
                hbf[node * 64 + f * 16 + l15] = f2bf(acc[f][r]);
        }
    }
}

// ---------------- CSR build: counting sort of edges by destination row -------
__global__ void count_kernel(const int* __restrict__ rows, int* __restrict__ counts, int E){
    for (int i = blockIdx.x * blockDim.x + threadIdx.x; i < E; i += gridDim.x * blockDim.x)
        atomicAdd(&counts[rows[i]], 1);
}

__global__ __launch_bounds__(1024) void scan_kernel(const int* __restrict__ counts,
                                                    int* __restrict__ cursor, int n)
{
    __shared__ int wsum[16];
    __shared__ int carry_s;
    const int tid = threadIdx.x, lane = tid & 63, wv = tid >> 6;
    if (tid == 0) carry_s = 0;
    __syncthreads();
    for (int base = 0; base < n; base += 1024){
        int i = base + tid;
        int x = (i < n) ? counts[i] : 0;
        int inc = x;
        #pragma unroll
        for (int d = 1; d < 64; d <<= 1){
            int t = __shfl_up(inc, d);
            if (lane >= d) inc += t;
        }
        if (lane == 63) wsum[wv] = inc;
        __syncthreads();
        if (tid < 16){
            int s = wsum[tid];
            int si = s;
            #pragma unroll
            for (int d = 1; d < 16; d <<= 1){
                int t = __shfl_up(si, d);
                if (tid >= d) si += t;
            }
            wsum[tid] = si - s;   // exclusive wave offset
        }
        __syncthreads();
        int excl = inc - x + wsum[wv] + carry_s;
        if (i < n) cursor[i] = excl;
        __syncthreads();
        if (tid == 1023) carry_s += wsum[15] + inc;
        __syncthreads();
    }
}

__global__ void scatter_kernel(const int* __restrict__ rows, int* __restrict__ cursor,
                               int* __restrict__ eperm, int E){
    for (int i = blockIdx.x * blockDim.x + threadIdx.x; i < E; i += gridDim.x * blockDim.x){
        int r = rows[i];
        int pos = atomicAdd(&cursor[r], 1);
        eperm[pos] = i;
    }
}

// ---------------- message + segmented scatter-add (row-sorted edges) ---------
__global__ __launch_bounds__(256) void msg_kernel(
    const u16* __restrict__ hbf, const int* __restrict__ rows, const int* __restrict__ cols,
    const int* __restrict__ eperm, const float* __restrict__ EF,
    const float* __restrict__ W1, const float* __restrict__ B1,
    const float* __restrict__ W2, const float* __restrict__ B2,
    float* __restrict__ agg, int E, int ntiles)
{
    __shared__ u16 sHid[64 * 72];
    __shared__ float sMsg[4][16 * 68];
    const int tid = threadIdx.x;
    const int w = tid >> 6, l = tid & 63, l15 = l & 15, quad = l >> 4;

    bf16x8 bW1a[2][4], bW1b[2][4], bW2[2][4];
    #pragma unroll
    for (int kk = 0; kk < 2; ++kk)
        #pragma unroll
        for (int f = 0; f < 4; ++f){
            int n = f * 16 + l15, k0 = kk * 32 + quad * 8;
            bW1a[kk][f] = load_bfrag(W1,           64, n, k0);
            bW1b[kk][f] = load_bfrag(W1 + 64 * 64, 64, n, k0);
            bW2 [kk][f] = load_bfrag(W2,           64, n, k0);
        }
    float bias1[4], wc0[4], wc1[4], bias2[4];
    #pragma unroll
    for (int f = 0; f < 4; ++f){
        int n = f * 16 + l15;
        bias1[f] = B1[n];
        wc0[f]   = W1[128 * 64 + n];
        wc1[f]   = W1[129 * 64 + n];
        bias2[f] = B2[n];
    }

    u16* myHid = sHid + (w * 16) * 72;
    float* myMsg = sMsg[w];

    for (int tile = blockIdx.x; tile < ntiles; tile += gridDim.x){
        const int ebase = tile * 64 + w * 16;

        // A-side gather: lane's A-row edge = ebase + l15 (row-sorted via eperm)
        int ea = ebase + l15;
        bool va = ea < E;
        int epa = eperm[va ? ea : 0];
        int rn = va ? rows[epa] : -1;       // -1 = sentinel (padded tail)
        int cn = cols[epa];
        int rga = va ? rn : 0;
        const u16* prow = hbf + (size_t)rga * 64 + quad * 8;
        const u16* pcol = hbf + (size_t)cn  * 64 + quad * 8;
        bf16x8 aR0 = *(const bf16x8*)(prow);
        bf16x8 aR1 = *(const bf16x8*)(prow + 32);
        bf16x8 aC0 = *(const bf16x8*)(pcol);
        bf16x8 aC1 = *(const bf16x8*)(pcol + 32);

        // edge features for accumulator rows (quad*4+r)
        float e0v[4], e1v[4];
        #pragma unroll
        for (int r = 0; r < 4; ++r){
            int e = ebase + quad * 4 + r;
            int ep = eperm[e < E ? e : 0];
            e0v[r] = EF[ep * 2]; e1v[r] = EF[ep * 2 + 1];
        }

        f32x4 acc[4];
        #pragma unroll
        for (int f = 0; f < 4; ++f)
            #pragma unroll
            for (int r = 0; r < 4; ++r)
                acc[f][r] = bias1[f] + e0v[r] * wc0[f] + e1v[r] * wc1[f];

        #pragma unroll
        for (int f = 0; f < 4; ++f) acc[f] = MFMA16(aR0, bW1a[0][f], acc[f]);
        #pragma unroll
        for (int f = 0; f < 4; ++f) acc[f] = MFMA16(aR1, bW1a[1][f], acc[f]);
        #pragma unroll
        for (int f = 0; f < 4; ++f) acc[f] = MFMA16(aC0, bW1b[0][f], acc[f]);
        #pragma unroll
        for (int f = 0; f < 4; ++f) acc[f] = MFMA16(aC1, bW1b[1][f], acc[f]);

        // relu -> bf16 -> LDS handoff (C-layout -> A-layout)
        #pragma unroll
        for (int f = 0; f < 4; ++f)
            #pragma unroll
            for (int r = 0; r < 4; ++r){
                float v = acc[f][r] > 0.f ? acc[f][r] : 0.f;
                myHid[(quad * 4 + r) * 72 + f * 16 + l15] = f2bf(v);
            }

        f32x4 m[4];
        #pragma unroll
        for (int f = 0; f < 4; ++f){ m[f][0]=bias2[f]; m[f][1]=bias2[f]; m[f][2]=bias2[f]; m[f][3]=bias2[f]; }
        #pragma unroll
        for (int kk = 0; kk < 2; ++kk){
            bf16x8 a = *(const bf16x8*)&myHid[l15 * 72 + kk * 32 + quad * 8];
            #pragma unroll
            for (int f = 0; f < 4; ++f) m[f] = MFMA16(a, bW2[kk][f], m[f]);
        }

        // messages -> LDS so that lane index = feature
        #pragma unroll
        for (int f = 0; f < 4; ++f)
            #pragma unroll
            for (int r = 0; r < 4; ++r)
                myMsg[(quad * 4 + r) * 68 + f * 16 + l15] = m[f][r];

        // segmented reduction over this wave's 16 row-sorted edges; one
        // coalesced 64-lane atomic per segment (avg ~2 segments / 16 edges)
        float accv = 0.f;
        int cur = __shfl(rn, 0);
        #pragma unroll
        for (int j = 0; j < 16; ++j){
            int rj = __shfl(rn, j);
            if (rj != cur){
                if (cur >= 0) atomicAdd(agg + (size_t)cur * 64 + l, accv);
                accv = 0.f; cur = rj;
            }
            accv += myMsg[j * 68 + l];
        }
        if (cur >= 0) atomicAdd(agg + (size_t)cur * 64 + l, accv);
    }
}

// ---------------- update: h = relu(LN(agg + h@skipW + skipB)) ----------------
__global__ __launch_bounds__(256) void update_kernel(
    u16* __restrict__ hbf, const float* __restrict__ agg,
    const float* __restrict__ SW, const float* __restrict__ SB,
    const float* __restrict__ LG, const float* __restrict__ LB, int N)
{
    const int tid = threadIdx.x;
    const int w = tid >> 6, l = tid & 63, l15 = l & 15, quad = l >> 4;

    bf16x8 bW[2][4];
    #pragma unroll
    for (int kk = 0; kk < 2; ++kk)
        #pragma unroll
        for (int f = 0; f < 4; ++f)
            bW[kk][f] = load_bfrag(SW, 64, f * 16 + l15, kk * 32 + quad * 8);
    float sb[4], lg[4], lb[4];
    #pragma unroll
    for (int f = 0; f < 4; ++f){
        int n = f * 16 + l15;
        sb[f] = SB[n]; lg[f] = LG[n]; lb[f] = LB[n];
    }

    const int nbase = blockIdx.x * 64 + w * 16;
    int na = nbase + l15; if (na > N - 1) na = N - 1;
    const u16* pa = hbf + (size_t)na * 64 + quad * 8;
    bf16x8 a0 = *(const bf16x8*)pa;
    bf16x8 a1 = *(const bf16x8*)(pa + 32);

    f32x4 acc[4] = {};
    #pragma unroll
    for (int f = 0; f < 4; ++f) acc[f] = MFMA16(a0, bW[0][f], acc[f]);
    #pragma unroll
    for (int f = 0; f < 4; ++f) acc[f] = MFMA16(a1, bW[1][f], acc[f]);

    float vals[4][4];
    #pragma unroll
    for (int r = 0; r < 4; ++r){
        int node = nbase + quad * 4 + r; if (node > N - 1) node = N - 1;
        #pragma unroll
        for (int f = 0; f < 4; ++f)
            vals[f][r] = acc[f][r] + sb[f] + agg[(size_t)node * 64 + f * 16 + l15];
    }

    #pragma unroll
    for (int r = 0; r < 4; ++r){
        float s  = vals[0][r] + vals[1][r] + vals[2][r] + vals[3][r];
        float sq = vals[0][r]*vals[0][r] + vals[1][r]*vals[1][r]
                 + vals[2][r]*vals[2][r] + vals[3][r]*vals[3][r];
        #pragma unroll
        for (int msk = 1; msk < 16; msk <<= 1){
            s  += __shfl_xor(s,  msk);
            sq += __shfl_xor(sq, msk);
        }
        float mean = s * (1.f / 64.f);
        float var  = sq * (1.f / 64.f) - mean * mean;
        float rstd = rsqrtf(var + 1e-5f);
        int node = nbase + quad * 4 + r;
        if (node < N){
            #pragma unroll
            for (int f = 0; f < 4; ++f){
                float hv = (vals[f][r] - mean) * rstd * lg[f] + lb[f];
                hv = hv > 0.f ? hv : 0.f;
                hbf[(size_t)node * 64 + f * 16 + l15] = f2bf(hv);
            }
        }
    }
}

// ---------------- head: out = relu(h@W1+b1)@W2 + b2  [N][8] f32 --------------
__global__ __launch_bounds__(256) void head_kernel(
    const u16* __restrict__ hbf,
    const float* __restrict__ W1, const float* __restrict__ B1,
    const float* __restrict__ W2, const float* __restrict__ B2,
    float* __restrict__ out, int N)
{
    __shared__ u16 sT[64 * 72];
    const int tid = threadIdx.x;
    const int w = tid >> 6, l = tid & 63, l15 = l & 15, quad = l >> 4;

    bf16x8 bW1[2][4];
    #pragma unroll
    for (int kk = 0; kk < 2; ++kk)
        #pragma unroll
        for (int f = 0; f < 4; ++f)
            bW1[kk][f] = load_bfrag(W1, 64, f * 16 + l15, kk * 32 + quad * 8);
    float b1v[4];
    #pragma unroll
    for (int f = 0; f < 4; ++f) b1v[f] = B1[f * 16 + l15];

    bf16x8 bW2[2];
    #pragma unroll
    for (int kk = 0; kk < 2; ++kk)
        #pragma unroll
        for (int j = 0; j < 8; ++j){
            int k = kk * 32 + quad * 8 + j;
            bW2[kk][j] = (l15 < 8) ? (short)f2bf(W2[k * 8 + l15]) : (short)0;
        }
    float b2v = (l15 < 8) ? B2[l15] : 0.f;

    const int nbase = blockIdx.x * 64 + w * 16;
    int na = nbase + l15; if (na > N - 1) na = N - 1;
    const u16* pa = hbf + (size_t)na * 64 + quad * 8;
    bf16x8 a0 = *(const bf16x8*)pa;
    bf16x8 a1 = *(const bf16x8*)(pa + 32);

    f32x4 acc[4];
    #pragma unroll
    for (int f = 0; f < 4; ++f){ acc[f][0]=b1v[f]; acc[f][1]=b1v[f]; acc[f][2]=b1v[f]; acc[f][3]=b1v[f]; }
    #pragma unroll
    for (int f = 0; f < 4; ++f) acc[f] = MFMA16(a0, bW1[0][f], acc[f]);
    #pragma unroll
    for (int f = 0; f < 4; ++f) acc[f] = MFMA16(a1, bW1[1][f], acc[f]);

    u16* myT = sT + (w * 16) * 72;
    #pragma unroll
    for (int f = 0; f < 4; ++f)
        #pragma unroll
        for (int r = 0; r < 4; ++r){
            float v = acc[f][r] > 0.f ? acc[f][r] : 0.f;
            myT[(quad * 4 + r) * 72 + f * 16 + l15] = f2bf(v);
        }

    f32x4 o = { b2v, b2v, b2v, b2v };
    #pragma unroll
    for (int kk = 0; kk < 2; ++kk){
        bf16x8 a = *(const bf16x8*)&myT[l15 * 72 + kk * 32 + quad * 8];
        o = MFMA16(a, bW2[kk], o);
    }
    #pragma unroll
    for (int r = 0; r < 4; ++r){
        int node = nbase + quad * 4 + r;
        if (node < N && l15 < 8)
            out[(size_t)node * 8 + l15] = o[r];
    }
}

extern "C" void kernel_launch(void* const* d_in, const int* in_sizes, int n_in,
                              void* d_out, int out_size, void* d_ws, size_t ws_size,
                              hipStream_t stream)
{
    const float* X      = (const float*)d_in[0];
    const int*   EI     = (const int*)d_in[1];
    const float* EF     = (const float*)d_in[2];
    const float* encW1  = (const float*)d_in[4];
    const float* encB1  = (const float*)d_in[5];
    const float* encW2  = (const float*)d_in[6];
    const float* encB2  = (const float*)d_in[7];
    const float* convW1 = (const float*)d_in[8];
    const float* convB1 = (const float*)d_in[9];
    const float* convW2 = (const float*)d_in[10];
    const float* convB2 = (const float*)d_in[11];
    const float* skipW  = (const float*)d_in[12];
    const float* skipB  = (const float*)d_in[13];
    const float* lnG    = (const float*)d_in[14];
    const float* lnB    = (const float*)d_in[15];
    const float* headW1 = (const float*)d_in[16];
    const float* headB1 = (const float*)d_in[17];
    const float* headW2 = (const float*)d_in[18];
    const float* headB2 = (const float*)d_in[19];

    const int N = in_sizes[0] / 3;
    const int E = in_sizes[1] / 2;
    const int L = in_sizes[8] / (130 * 64);
    const int* rows = EI;
    const int* cols = EI + E;

    u16*   hbf = (u16*)d_ws;
    size_t hbf_bytes = (((size_t)N * 64 * sizeof(u16)) + 255) & ~(size_t)255;
    float* agg = (float*)((char*)d_ws + hbf_bytes);
    size_t agg_bytes = (((size_t)N * 64 * sizeof(float)) + 255) & ~(size_t)255;
    int*   eperm = (int*)((char*)d_ws + hbf_bytes + agg_bytes);

    // CSR-build scratch overlaid on agg (agg is re-zeroed per layer afterwards)
    int* counts = (int*)agg;
    int* cursor = counts + ((N + 63) & ~63);

    const int ntilesN = (N + 63) / 64;
    const int ntilesE = (E + 63) / 64;
    const int msg_blocks = ntilesE < 1024 ? ntilesE : 1024;

    // one-time edge sort by destination row (counting sort)
    hipMemsetAsync(counts, 0, (size_t)N * sizeof(int), stream);
    count_kernel<<<1024, 256, 0, stream>>>(rows, counts, E);
    scan_kernel<<<1, 1024, 0, stream>>>(counts, cursor, N);
    scatter_kernel<<<1024, 256, 0, stream>>>(rows, cursor, eperm, E);

    enc_kernel<<<ntilesN, 256, 0, stream>>>(X, encW1, encB1, encW2, encB2, hbf, N);
    for (int li = 0; li < L; ++li){
        hipMemsetAsync(agg, 0, (size_t)N * 64 * sizeof(float), stream);
        msg_kernel<<<msg_blocks, 256, 0, stream>>>(hbf, rows, cols, eperm, EF,
            convW1 + (size_t)li * 130 * 64, convB1 + li * 64,
            convW2 + (size_t)li * 64 * 64, convB2 + li * 64,
            agg, E, ntilesE);
        update_kernel<<<ntilesN, 256, 0, stream>>>(hbf, agg,
            skipW + (size_t)li * 64 * 64, skipB + li * 64,
            lnG + li * 64, lnB + li * 64, N);
    }
    head_kernel<<<ntilesN, 256, 0, stream>>>(hbf, headW1, headB1, headW2, headB2,
                                             (float*)d_out, N);
}

// Round 3
// 415.237 us; speedup vs baseline: 1.9291x; 1.5086x over previous
//
#include <hip/hip_runtime.h>

typedef unsigned short u16;
typedef __attribute__((ext_vector_type(8))) short bf16x8;
typedef __attribute__((ext_vector_type(4))) float f32x4;

#define MFMA16(a,b,c) __builtin_amdgcn_mfma_f32_16x16x32_bf16((a),(b),(c),0,0,0)

static __device__ __forceinline__ u16 f2bf(float x){
    unsigned int u = __float_as_uint(x);
    u += 0x7FFFu + ((u >> 16) & 1u);
    return (u16)(u >> 16);
}
static __device__ __forceinline__ float bf2f(short s){
    return __uint_as_float(((unsigned int)(u16)s) << 16);
}

static __device__ __forceinline__ bf16x8 load_bfrag(const float* __restrict__ W, int ldn, int n, int k0){
    bf16x8 r;
    #pragma unroll
    for (int j = 0; j < 8; ++j) r[j] = (short)f2bf(W[(k0 + j) * ldn + n]);
    return r;
}

// ---------------- encoder: h = relu(x@W1+b1)@W2 + b2 ; emit h, U0, V0 --------
__global__ __launch_bounds__(256) void enc_kernel(
    const float* __restrict__ X, const float* __restrict__ W1, const float* __restrict__ B1,
    const float* __restrict__ W2, const float* __restrict__ B2,
    const float* __restrict__ cW1, const float* __restrict__ cB1,   // conv layer-0
    u16* __restrict__ hbf, u16* __restrict__ Ubf, u16* __restrict__ Vbf, int N)
{
    __shared__ u16 sHid[64 * 136];
    __shared__ u16 sH[64 * 72];
    const int tid = threadIdx.x;
    const int w = tid >> 6, l = tid & 63, l15 = l & 15, quad = l >> 4;

    bf16x8 bW[4][4];
    #pragma unroll
    for (int ks = 0; ks < 4; ++ks)
        #pragma unroll
        for (int f = 0; f < 4; ++f)
            bW[ks][f] = load_bfrag(W2, 64, f * 16 + l15, ks * 32 + quad * 8);
    float b2v[4];
    #pragma unroll
    for (int f = 0; f < 4; ++f) b2v[f] = B2[f * 16 + l15];

    const int nbase = blockIdx.x * 64 + w * 16;

    {
        int e = l >> 2;
        int node = nbase + e; if (node > N - 1) node = N - 1;
        float x0 = X[node * 3], x1 = X[node * 3 + 1], x2 = X[node * 3 + 2];
        int k0 = (l & 3) * 32;
        u16* dst = sHid + (w * 16 + e) * 136 + k0;
        #pragma unroll
        for (int j = 0; j < 32; ++j){
            int k = k0 + j;
            float hv = x0 * W1[k] + x1 * W1[128 + k] + x2 * W1[256 + k] + B1[k];
            dst[j] = f2bf(hv > 0.f ? hv : 0.f);
        }
    }

    f32x4 acc[4];
    #pragma unroll
    for (int f = 0; f < 4; ++f){ acc[f][0]=b2v[f]; acc[f][1]=b2v[f]; acc[f][2]=b2v[f]; acc[f][3]=b2v[f]; }
    #pragma unroll
    for (int ks = 0; ks < 4; ++ks){
        bf16x8 a = *(const bf16x8*)&sHid[(w * 16 + l15) * 136 + ks * 32 + quad * 8];
        #pragma unroll
        for (int f = 0; f < 4; ++f) acc[f] = MFMA16(a, bW[ks][f], acc[f]);
    }
    #pragma unroll
    for (int r = 0; r < 4; ++r){
        int node = nbase + quad * 4 + r;
        #pragma unroll
        for (int f = 0; f < 4; ++f){
            u16 hb = f2bf(acc[f][r]);
            sH[(w * 16 + quad * 4 + r) * 72 + f * 16 + l15] = hb;
            if (node < N) hbf[(size_t)node * 64 + f * 16 + l15] = hb;
        }
    }

    // U = h@cW1a + cB1 ; V = h@cW1b   (same-wave LDS write->read, no barrier)
    bf16x8 bA[2][4], bB[2][4];
    #pragma unroll
    for (int kk = 0; kk < 2; ++kk)
        #pragma unroll
        for (int f = 0; f < 4; ++f){
            int n = f * 16 + l15, k0 = kk * 32 + quad * 8;
            bA[kk][f] = load_bfrag(cW1,           64, n, k0);
            bB[kk][f] = load_bfrag(cW1 + 64 * 64, 64, n, k0);
        }
    float b1n[4];
    #pragma unroll
    for (int f = 0; f < 4; ++f) b1n[f] = cB1[f * 16 + l15];

    bf16x8 a0 = *(const bf16x8*)&sH[(w * 16 + l15) * 72 + quad * 8];
    bf16x8 a1 = *(const bf16x8*)&sH[(w * 16 + l15) * 72 + 32 + quad * 8];

    f32x4 ua[4], va[4];
    #pragma unroll
    for (int f = 0; f < 4; ++f){
        ua[f][0]=b1n[f]; ua[f][1]=b1n[f]; ua[f][2]=b1n[f]; ua[f][3]=b1n[f];
        va[f][0]=0.f; va[f][1]=0.f; va[f][2]=0.f; va[f][3]=0.f;
    }
    #pragma unroll
    for (int f = 0; f < 4; ++f){ ua[f] = MFMA16(a0, bA[0][f], ua[f]); va[f] = MFMA16(a0, bB[0][f], va[f]); }
    #pragma unroll
    for (int f = 0; f < 4; ++f){ ua[f] = MFMA16(a1, bA[1][f], ua[f]); va[f] = MFMA16(a1, bB[1][f], va[f]); }

    #pragma unroll
    for (int r = 0; r < 4; ++r){
        int node = nbase + quad * 4 + r;
        if (node < N){
            #pragma unroll
            for (int f = 0; f < 4; ++f){
                Ubf[(size_t)node * 64 + f * 16 + l15] = f2bf(ua[f][r]);
                Vbf[(size_t)node * 64 + f * 16 + l15] = f2bf(va[f][r]);
            }
        }
    }
}

// ---------------- sort/pack build -------------------------------------------
__global__ void count_kernel(const int* __restrict__ rows, int* __restrict__ counts, int E){
    for (int i = blockIdx.x * blockDim.x + threadIdx.x; i < E; i += gridDim.x * blockDim.x)
        atomicAdd(&counts[rows[i]], 1);
}

__global__ __launch_bounds__(1024) void scan_partial(const int* __restrict__ counts,
                                                     int* __restrict__ cursor,
                                                     int* __restrict__ tops, int n)
{
    __shared__ int wsum[16];
    const int tid = threadIdx.x, lane = tid & 63, wv = tid >> 6;
    int i = blockIdx.x * 1024 + tid;
    int x = (i < n) ? counts[i] : 0;
    int inc = x;
    #pragma unroll
    for (int d = 1; d < 64; d <<= 1){
        int t = __shfl_up(inc, d);
        if (lane >= d) inc += t;
    }
    if (lane == 63) wsum[wv] = inc;
    __syncthreads();
    if (tid < 16){
        int s = wsum[tid], si = s;
        #pragma unroll
        for (int d = 1; d < 16; d <<= 1){
            int t = __shfl_up(si, d);
            if (tid >= d) si += t;
        }
        wsum[tid] = si - s;
    }
    __syncthreads();
    int excl = inc - x + wsum[wv];
    if (i < n) cursor[i] = excl;
    if (tid == 1023) tops[blockIdx.x] = wsum[15] + inc;
}

__global__ __launch_bounds__(1024) void scan_tops(int* __restrict__ tops, int nb){
    __shared__ int wsum[16];
    const int tid = threadIdx.x, lane = tid & 63, wv = tid >> 6;
    int x = (tid < nb) ? tops[tid] : 0;
    int inc = x;
    #pragma unroll
    for (int d = 1; d < 64; d <<= 1){
        int t = __shfl_up(inc, d);
        if (lane >= d) inc += t;
    }
    if (lane == 63) wsum[wv] = inc;
    __syncthreads();
    if (tid < 16){
        int s = wsum[tid], si = s;
        #pragma unroll
        for (int d = 1; d < 16; d <<= 1){
            int t = __shfl_up(si, d);
            if (tid >= d) si += t;
        }
        wsum[tid] = si - s;
    }
    __syncthreads();
    if (tid < nb) tops[tid] = inc - x + wsum[wv];
}

__global__ __launch_bounds__(1024) void scan_add(int* __restrict__ cursor,
                                                 const int* __restrict__ tops, int n){
    int i = blockIdx.x * 1024 + threadIdx.x;
    if (i < n) cursor[i] += tops[blockIdx.x];
}

__global__ void pack_kernel(const int* __restrict__ rows, const int* __restrict__ cols,
                            const float* __restrict__ EF, int* __restrict__ cursor,
                            int4* __restrict__ erec, int E){
    for (int i = blockIdx.x * blockDim.x + threadIdx.x; i < E; i += gridDim.x * blockDim.x){
        int r = rows[i];
        int pos = atomicAdd(&cursor[r], 1);
        float2 ef = *(const float2*)&EF[2 * i];
        int4 v;
        v.x = r; v.y = cols[i];
        v.z = __float_as_int(ef.x); v.w = __float_as_int(ef.y);
        erec[pos] = v;
    }
}

__global__ void pad_kernel(int4* __restrict__ erec, int E, int Epad){
    int i = E + blockIdx.x * blockDim.x + threadIdx.x;
    if (i < Epad){ int4 v; v.x = -1; v.y = 0; v.z = 0; v.w = 0; erec[i] = v; }
}

// ---------------- message: hid = relu(U[r]+V[c]+ef·W1c); msg = hid@W2+b2 -----
__global__ __launch_bounds__(256, 3) void msg_kernel(
    const u16* __restrict__ Ubf, const u16* __restrict__ Vbf,
    const int4* __restrict__ erec,
    const float* __restrict__ W1,   // [130][64] of this layer (ef rows 128,129)
    const float* __restrict__ W2, const float* __restrict__ B2,
    float* __restrict__ agg, int ntiles, int ipb)
{
    __shared__ float sMsg[4][16 * 68];
    const int tid = threadIdx.x;
    const int w = tid >> 6, l = tid & 63, l15 = l & 15, quad = l >> 4;
    const int w16 = w * 16;

    bf16x8 bW2[2][4];
    #pragma unroll
    for (int kk = 0; kk < 2; ++kk)
        #pragma unroll
        for (int f = 0; f < 4; ++f)
            bW2[kk][f] = load_bfrag(W2, 64, f * 16 + l15, kk * 32 + quad * 8);
    float bias2[4];
    #pragma unroll
    for (int f = 0; f < 4; ++f) bias2[f] = B2[f * 16 + l15];

    // per-lane ef-row weights at k = quad*8+j (lo) and 32+quad*8+j (hi)
    const float* Wc0 = W1 + 128 * 64;
    const float* Wc1 = W1 + 129 * 64;
    float e0l[8], e0h[8], e1l[8], e1h[8];
    #pragma unroll
    for (int j = 0; j < 8; ++j){
        int kl = quad * 8 + j;
        e0l[j] = Wc0[kl];       e0h[j] = Wc0[32 + kl];
        e1l[j] = Wc1[kl];       e1h[j] = Wc1[32 + kl];
    }

    float* myMsg = sMsg[w];

    int tstart = blockIdx.x * ipb;
    int tend = tstart + ipb; if (tend > ntiles) tend = ntiles;
    if (tstart >= tend) return;

    int4 rec = erec[(size_t)tstart * 64 + w16 + l15];

    for (int t = tstart; t < tend; ++t){
        const int rn = rec.x, cn = rec.y;
        const float ef0 = __int_as_float(rec.z), ef1 = __int_as_float(rec.w);
        const int rg = rn < 0 ? 0 : rn;

        // A-layout gathers (lane = k-slice quad*8.., edge = l15)
        const u16* pu = Ubf + (size_t)rg * 64 + quad * 8;
        const u16* pv = Vbf + (size_t)cn * 64 + quad * 8;
        bf16x8 u0 = *(const bf16x8*)(pu);
        bf16x8 u1 = *(const bf16x8*)(pu + 32);
        bf16x8 v0 = *(const bf16x8*)(pv);
        bf16x8 v1 = *(const bf16x8*)(pv + 32);

        // prefetch next tile's record
        int4 rec_n = rec;
        if (t + 1 < tend) rec_n = erec[(size_t)(t + 1) * 64 + w16 + l15];

        // independent ef contribution while gathers are in flight
        float hA[8], hB[8];
        #pragma unroll
        for (int j = 0; j < 8; ++j){
            hA[j] = fmaf(ef1, e1l[j], ef0 * e0l[j]);
            hB[j] = fmaf(ef1, e1h[j], ef0 * e0h[j]);
        }

        bf16x8 a0, a1;
        #pragma unroll
        for (int j = 0; j < 8; ++j){
            float xl = hA[j] + bf2f(u0[j]) + bf2f(v0[j]);
            float xh = hB[j] + bf2f(u1[j]) + bf2f(v1[j]);
            a0[j] = (short)f2bf(xl > 0.f ? xl : 0.f);
            a1[j] = (short)f2bf(xh > 0.f ? xh : 0.f);
        }

        f32x4 m[4];
        #pragma unroll
        for (int f = 0; f < 4; ++f){ m[f][0]=bias2[f]; m[f][1]=bias2[f]; m[f][2]=bias2[f]; m[f][3]=bias2[f]; }
        #pragma unroll
        for (int f = 0; f < 4; ++f) m[f] = MFMA16(a0, bW2[0][f], m[f]);
        #pragma unroll
        for (int f = 0; f < 4; ++f) m[f] = MFMA16(a1, bW2[1][f], m[f]);

        // C-layout messages -> LDS so lane = feature
        #pragma unroll
        for (int f = 0; f < 4; ++f)
            #pragma unroll
            for (int r = 0; r < 4; ++r)
                myMsg[(quad * 4 + r) * 68 + f * 16 + l15] = m[f][r];

        // segmented reduction over 16 row-sorted edges
        float accv = 0.f;
        int cur = __shfl(rn, 0);
        #pragma unroll
        for (int j = 0; j < 16; ++j){
            int rj = __shfl(rn, j);
            if (rj != cur){
                if (cur >= 0) atomicAdd(agg + (size_t)cur * 64 + l, accv);
                accv = 0.f; cur = rj;
            }
            accv += myMsg[j * 68 + l];
        }
        if (cur >= 0) atomicAdd(agg + (size_t)cur * 64 + l, accv);

        rec = rec_n;
    }
}

// ------- update: h = relu(LN(agg + h@SW + SB)); zero agg; emit U,V next -----
__global__ __launch_bounds__(256) void update_kernel(
    u16* __restrict__ hbf, float* __restrict__ agg,
    const float* __restrict__ SW, const float* __restrict__ SB,
    const float* __restrict__ LG, const float* __restrict__ LB,
    const float* __restrict__ cW1, const float* __restrict__ cB1,  // next layer (may be null)
    u16* __restrict__ Ubf, u16* __restrict__ Vbf, int N)
{
    __shared__ u16 sH[64 * 72];
    const int tid = threadIdx.x;
    const int w = tid >> 6, l = tid & 63, l15 = l & 15, quad = l >> 4;

    bf16x8 bW[2][4];
    #pragma unroll
    for (int kk = 0; kk < 2; ++kk)
        #pragma unroll
        for (int f = 0; f < 4; ++f)
            bW[kk][f] = load_bfrag(SW, 64, f * 16 + l15, kk * 32 + quad * 8);
    float sb[4], lg[4], lb[4];
    #pragma unroll
    for (int f = 0; f < 4; ++f){
        int n = f * 16 + l15;
        sb[f] = SB[n]; lg[f] = LG[n]; lb[f] = LB[n];
    }

    const int nbase = blockIdx.x * 64 + w * 16;
    int na = nbase + l15; if (na > N - 1) na = N - 1;
    const u16* pa = hbf + (size_t)na * 64 + quad * 8;
    bf16x8 h0 = *(const bf16x8*)pa;
    bf16x8 h1 = *(const bf16x8*)(pa + 32);

    f32x4 acc[4] = {};
    #pragma unroll
    for (int f = 0; f < 4; ++f) acc[f] = MFMA16(h0, bW[0][f], acc[f]);
    #pragma unroll
    for (int f = 0; f < 4; ++f) acc[f] = MFMA16(h1, bW[1][f], acc[f]);

    float vals[4][4];
    #pragma unroll
    for (int r = 0; r < 4; ++r){
        int node = nbase + quad * 4 + r; if (node > N - 1) node = N - 1;
        #pragma unroll
        for (int f = 0; f < 4; ++f)
            vals[f][r] = acc[f][r] + sb[f] + agg[(size_t)node * 64 + f * 16 + l15];
    }

    #pragma unroll
    for (int r = 0; r < 4; ++r){
        float s  = vals[0][r] + vals[1][r] + vals[2][r] + vals[3][r];
        float sq = vals[0][r]*vals[0][r] + vals[1][r]*vals[1][r]
                 + vals[2][r]*vals[2][r] + vals[3][r]*vals[3][r];
        #pragma unroll
        for (int msk = 1; msk < 16; msk <<= 1){
            s  += __shfl_xor(s,  msk);
            sq += __shfl_xor(sq, msk);
        }
        float mean = s * (1.f / 64.f);
        float var  = sq * (1.f / 64.f) - mean * mean;
        float rstd = rsqrtf(var + 1e-5f);
        int node = nbase + quad * 4 + r;
        #pragma unroll
        for (int f = 0; f < 4; ++f){
            float hv = (vals[f][r] - mean) * rstd * lg[f] + lb[f];
            hv = hv > 0.f ? hv : 0.f;
            u16 hb = f2bf(hv);
            sH[(w * 16 + quad * 4 + r) * 72 + f * 16 + l15] = hb;
            if (node < N){
                hbf[(size_t)node * 64 + f * 16 + l15] = hb;
                agg[(size_t)node * 64 + f * 16 + l15] = 0.f;   // ready for next layer
            }
        }
    }

    if (cW1){
        bf16x8 bA[2][4], bB[2][4];
        #pragma unroll
        for (int kk = 0; kk < 2; ++kk)
            #pragma unroll
            for (int f = 0; f < 4; ++f){
                int n = f * 16 + l15, k0 = kk * 32 + quad * 8;
                bA[kk][f] = load_bfrag(cW1,           64, n, k0);
                bB[kk][f] = load_bfrag(cW1 + 64 * 64, 64, n, k0);
            }
        float b1n[4];
        #pragma unroll
        for (int f = 0; f < 4; ++f) b1n[f] = cB1[f * 16 + l15];

        bf16x8 a0 = *(const bf16x8*)&sH[(w * 16 + l15) * 72 + quad * 8];
        bf16x8 a1 = *(const bf16x8*)&sH[(w * 16 + l15) * 72 + 32 + quad * 8];

        f32x4 ua[4], va[4];
        #pragma unroll
        for (int f = 0; f < 4; ++f){
            ua[f][0]=b1n[f]; ua[f][1]=b1n[f]; ua[f][2]=b1n[f]; ua[f][3]=b1n[f];
            va[f][0]=0.f; va[f][1]=0.f; va[f][2]=0.f; va[f][3]=0.f;
        }
        #pragma unroll
        for (int f = 0; f < 4; ++f){ ua[f] = MFMA16(a0, bA[0][f], ua[f]); va[f] = MFMA16(a0, bB[0][f], va[f]); }
        #pragma unroll
        for (int f = 0; f < 4; ++f){ ua[f] = MFMA16(a1, bA[1][f], ua[f]); va[f] = MFMA16(a1, bB[1][f], va[f]); }

        #pragma unroll
        for (int r = 0; r < 4; ++r){
            int node = nbase + quad * 4 + r;
            if (node < N){
                #pragma unroll
                for (int f = 0; f < 4; ++f){
                    Ubf[(size_t)node * 64 + f * 16 + l15] = f2bf(ua[f][r]);
                    Vbf[(size_t)node * 64 + f * 16 + l15] = f2bf(va[f][r]);
                }
            }
        }
    }
}

// ---------------- head: out = relu(h@W1+b1)@W2 + b2  [N][8] f32 --------------
__global__ __launch_bounds__(256) void head_kernel(
    const u16* __restrict__ hbf,
    const float* __restrict__ W1, const float* __restrict__ B1,
    const float* __restrict__ W2, const float* __restrict__ B2,
    float* __restrict__ out, int N)
{
    __shared__ u16 sT[64 * 72];
    const int tid = threadIdx.x;
    const int w = tid >> 6, l = tid & 63, l15 = l & 15, quad = l >> 4;

    bf16x8 bW1[2][4];
    #pragma unroll
    for (int kk = 0; kk < 2; ++kk)
        #pragma unroll
        for (int f = 0; f < 4; ++f)
            bW1[kk][f] = load_bfrag(W1, 64, f * 16 + l15, kk * 32 + quad * 8);
    float b1v[4];
    #pragma unroll
    for (int f = 0; f < 4; ++f) b1v[f] = B1[f * 16 + l15];

    bf16x8 bW2[2];
    #pragma unroll
    for (int kk = 0; kk < 2; ++kk)
        #pragma unroll
        for (int j = 0; j < 8; ++j){
            int k = kk * 32 + quad * 8 + j;
            bW2[kk][j] = (l15 < 8) ? (short)f2bf(W2[k * 8 + l15]) : (short)0;
        }
    float b2v = (l15 < 8) ? B2[l15] : 0.f;

    const int nbase = blockIdx.x * 64 + w * 16;
    int na = nbase + l15; if (na > N - 1) na = N - 1;
    const u16* pa = hbf + (size_t)na * 64 + quad * 8;
    bf16x8 a0 = *(const bf16x8*)pa;
    bf16x8 a1 = *(const bf16x8*)(pa + 32);

    f32x4 acc[4];
    #pragma unroll
    for (int f = 0; f < 4; ++f){ acc[f][0]=b1v[f]; acc[f][1]=b1v[f]; acc[f][2]=b1v[f]; acc[f][3]=b1v[f]; }
    #pragma unroll
    for (int f = 0; f < 4; ++f) acc[f] = MFMA16(a0, bW1[0][f], acc[f]);
    #pragma unroll
    for (int f = 0; f < 4; ++f) acc[f] = MFMA16(a1, bW1[1][f], acc[f]);

    u16* myT = sT + (w * 16) * 72;
    #pragma unroll
    for (int f = 0; f < 4; ++f)
        #pragma unroll
        for (int r = 0; r < 4; ++r){
            float v = acc[f][r] > 0.f ? acc[f][r] : 0.f;
            myT[(quad * 4 + r) * 72 + f * 16 + l15] = f2bf(v);
        }

    f32x4 o = { b2v, b2v, b2v, b2v };
    #pragma unroll
    for (int kk = 0; kk < 2; ++kk){
        bf16x8 a = *(const bf16x8*)&myT[l15 * 72 + kk * 32 + quad * 8];
        o = MFMA16(a, bW2[kk], o);
    }
    #pragma unroll
    for (int r = 0; r < 4; ++r){
        int node = nbase + quad * 4 + r;
        if (node < N && l15 < 8)
            out[(size_t)node * 8 + l15] = o[r];
    }
}

extern "C" void kernel_launch(void* const* d_in, const int* in_sizes, int n_in,
                              void* d_out, int out_size, void* d_ws, size_t ws_size,
                              hipStream_t stream)
{
    const float* X      = (const float*)d_in[0];
    const int*   EI     = (const int*)d_in[1];
    const float* EF     = (const float*)d_in[2];
    const float* encW1  = (const float*)d_in[4];
    const float* encB1  = (const float*)d_in[5];
    const float* encW2  = (const float*)d_in[6];
    const float* encB2  = (const float*)d_in[7];
    const float* convW1 = (const float*)d_in[8];
    const float* convB1 = (const float*)d_in[9];
    const float* convW2 = (const float*)d_in[10];
    const float* convB2 = (const float*)d_in[11];
    const float* skipW  = (const float*)d_in[12];
    const float* skipB  = (const float*)d_in[13];
    const float* lnG    = (const float*)d_in[14];
    const float* lnB    = (const float*)d_in[15];
    const float* headW1 = (const float*)d_in[16];
    const float* headB1 = (const float*)d_in[17];
    const float* headW2 = (const float*)d_in[18];
    const float* headB2 = (const float*)d_in[19];

    const int N = in_sizes[0] / 3;
    const int E = in_sizes[1] / 2;
    const int L = in_sizes[8] / (130 * 64);
    const int* rows = EI;
    const int* cols = EI + E;

    const int ntilesN = (N + 63) / 64;
    const int ntilesE = (E + 63) / 64;
    const int Epad = ntilesE * 64;

    auto align256 = [](size_t x){ return (x + 255) & ~(size_t)255; };
    char* p = (char*)d_ws;
    u16* hbf = (u16*)p;             p += align256((size_t)N * 64 * 2);
    u16* Ubf = (u16*)p;             p += align256((size_t)N * 64 * 2);
    u16* Vbf = (u16*)p;             p += align256((size_t)N * 64 * 2);
    float* agg = (float*)p;         p += align256((size_t)N * 64 * 4);
    int4* erec = (int4*)p;          p += align256((size_t)Epad * 16);
    int* counts = (int*)p;          p += align256((size_t)N * 4);
    int* cursor = (int*)p;          p += align256((size_t)N * 4);
    int* tops = (int*)p;            p += align256(4096);

    const int nblkS = (N + 1023) / 1024;

    // ---- build sorted packed edge records (once per call) ----
    hipMemsetAsync(counts, 0, (size_t)N * sizeof(int), stream);
    count_kernel<<<640, 256, 0, stream>>>(rows, counts, E);
    scan_partial<<<nblkS, 1024, 0, stream>>>(counts, cursor, tops, N);
    scan_tops<<<1, 1024, 0, stream>>>(tops, nblkS);
    scan_add<<<nblkS, 1024, 0, stream>>>(cursor, tops, N);
    pack_kernel<<<640, 256, 0, stream>>>(rows, cols, EF, cursor, erec, E);
    if (Epad > E)
        pad_kernel<<<(Epad - E + 255) / 256, 256, 0, stream>>>(erec, E, Epad);

    hipMemsetAsync(agg, 0, (size_t)N * 64 * sizeof(float), stream);
    enc_kernel<<<ntilesN, 256, 0, stream>>>(X, encW1, encB1, encW2, encB2,
                                            convW1, convB1, hbf, Ubf, Vbf, N);

    const int msg_blocks = 1024;
    const int ipb = (ntilesE + msg_blocks - 1) / msg_blocks;

    for (int li = 0; li < L; ++li){
        msg_kernel<<<msg_blocks, 256, 0, stream>>>(Ubf, Vbf, erec,
            convW1 + (size_t)li * 130 * 64,
            convW2 + (size_t)li * 64 * 64, convB2 + li * 64,
            agg, ntilesE, ipb);
        const float* w1n = (li + 1 < L) ? convW1 + (size_t)(li + 1) * 130 * 64 : nullptr;
        const float* b1n = (li + 1 < L) ? convB1 + (li + 1) * 64 : nullptr;
        update_kernel<<<ntilesN, 256, 0, stream>>>(hbf, agg,
            skipW + (size_t)li * 64 * 64, skipB + li * 64,
            lnG + li * 64, lnB + li * 64, w1n, b1n, Ubf, Vbf, N);
    }
    head_kernel<<<ntilesN, 256, 0, stream>>>(hbf, headW1, headB1, headW2, headB2,
                                             (float*)d_out, N);
}

// Round 4
// 389.341 us; speedup vs baseline: 2.0574x; 1.0665x over previous
//
#include <hip/hip_runtime.h>

typedef unsigned short u16;
typedef __attribute__((ext_vector_type(8))) short bf16x8;
typedef __attribute__((ext_vector_type(4))) float f32x4;

#define MFMA16(a,b,c) __builtin_amdgcn_mfma_f32_16x16x32_bf16((a),(b),(c),0,0,0)

static __device__ __forceinline__ u16 f2bf(float x){
    unsigned int u = __float_as_uint(x);
    u += 0x7FFFu + ((u >> 16) & 1u);
    return (u16)(u >> 16);
}
static __device__ __forceinline__ float bf2f(short s){
    return __uint_as_float(((unsigned int)(u16)s) << 16);
}

static __device__ __forceinline__ bf16x8 load_bfrag(const float* __restrict__ W, int ldn, int n, int k0){
    bf16x8 r;
    #pragma unroll
    for (int j = 0; j < 8; ++j) r[j] = (short)f2bf(W[(k0 + j) * ldn + n]);
    return r;
}

// ---------------- encoder: h = relu(x@W1+b1)@W2 + b2 ; emit h, U0, V0 --------
__global__ __launch_bounds__(256) void enc_kernel(
    const float* __restrict__ X, const float* __restrict__ W1, const float* __restrict__ B1,
    const float* __restrict__ W2, const float* __restrict__ B2,
    const float* __restrict__ cW1, const float* __restrict__ cB1,   // conv layer-0
    u16* __restrict__ hbf, u16* __restrict__ Ubf, u16* __restrict__ Vbf, int N)
{
    __shared__ u16 sHid[64 * 136];
    __shared__ u16 sH[64 * 72];
    const int tid = threadIdx.x;
    const int w = tid >> 6, l = tid & 63, l15 = l & 15, quad = l >> 4;

    bf16x8 bW[4][4];
    #pragma unroll
    for (int ks = 0; ks < 4; ++ks)
        #pragma unroll
        for (int f = 0; f < 4; ++f)
            bW[ks][f] = load_bfrag(W2, 64, f * 16 + l15, ks * 32 + quad * 8);
    float b2v[4];
    #pragma unroll
    for (int f = 0; f < 4; ++f) b2v[f] = B2[f * 16 + l15];

    const int nbase = blockIdx.x * 64 + w * 16;

    {
        int e = l >> 2;
        int node = nbase + e; if (node > N - 1) node = N - 1;
        float x0 = X[node * 3], x1 = X[node * 3 + 1], x2 = X[node * 3 + 2];
        int k0 = (l & 3) * 32;
        u16* dst = sHid + (w * 16 + e) * 136 + k0;
        #pragma unroll
        for (int j = 0; j < 32; ++j){
            int k = k0 + j;
            float hv = x0 * W1[k] + x1 * W1[128 + k] + x2 * W1[256 + k] + B1[k];
            dst[j] = f2bf(hv > 0.f ? hv : 0.f);
        }
    }

    f32x4 acc[4];
    #pragma unroll
    for (int f = 0; f < 4; ++f){ acc[f][0]=b2v[f]; acc[f][1]=b2v[f]; acc[f][2]=b2v[f]; acc[f][3]=b2v[f]; }
    #pragma unroll
    for (int ks = 0; ks < 4; ++ks){
        bf16x8 a = *(const bf16x8*)&sHid[(w * 16 + l15) * 136 + ks * 32 + quad * 8];
        #pragma unroll
        for (int f = 0; f < 4; ++f) acc[f] = MFMA16(a, bW[ks][f], acc[f]);
    }
    #pragma unroll
    for (int r = 0; r < 4; ++r){
        int node = nbase + quad * 4 + r;
        #pragma unroll
        for (int f = 0; f < 4; ++f){
            u16 hb = f2bf(acc[f][r]);
            sH[(w * 16 + quad * 4 + r) * 72 + f * 16 + l15] = hb;
            if (node < N) hbf[(size_t)node * 64 + f * 16 + l15] = hb;
        }
    }

    // U = h@cW1a + cB1 ; V = h@cW1b   (same-wave LDS write->read, no barrier)
    bf16x8 bA[2][4], bB[2][4];
    #pragma unroll
    for (int kk = 0; kk < 2; ++kk)
        #pragma unroll
        for (int f = 0; f < 4; ++f){
            int n = f * 16 + l15, k0 = kk * 32 + quad * 8;
            bA[kk][f] = load_bfrag(cW1,           64, n, k0);
            bB[kk][f] = load_bfrag(cW1 + 64 * 64, 64, n, k0);
        }
    float b1n[4];
    #pragma unroll
    for (int f = 0; f < 4; ++f) b1n[f] = cB1[f * 16 + l15];

    bf16x8 a0 = *(const bf16x8*)&sH[(w * 16 + l15) * 72 + quad * 8];
    bf16x8 a1 = *(const bf16x8*)&sH[(w * 16 + l15) * 72 + 32 + quad * 8];

    f32x4 ua[4], va[4];
    #pragma unroll
    for (int f = 0; f < 4; ++f){
        ua[f][0]=b1n[f]; ua[f][1]=b1n[f]; ua[f][2]=b1n[f]; ua[f][3]=b1n[f];
        va[f][0]=0.f; va[f][1]=0.f; va[f][2]=0.f; va[f][3]=0.f;
    }
    #pragma unroll
    for (int f = 0; f < 4; ++f){ ua[f] = MFMA16(a0, bA[0][f], ua[f]); va[f] = MFMA16(a0, bB[0][f], va[f]); }
    #pragma unroll
    for (int f = 0; f < 4; ++f){ ua[f] = MFMA16(a1, bA[1][f], ua[f]); va[f] = MFMA16(a1, bB[1][f], va[f]); }

    #pragma unroll
    for (int r = 0; r < 4; ++r){
        int node = nbase + quad * 4 + r;
        if (node < N){
            #pragma unroll
            for (int f = 0; f < 4; ++f){
                Ubf[(size_t)node * 64 + f * 16 + l15] = f2bf(ua[f][r]);
                Vbf[(size_t)node * 64 + f * 16 + l15] = f2bf(va[f][r]);
            }
        }
    }
}

// ---------------- sort/pack build -------------------------------------------
__global__ void count_kernel(const int* __restrict__ rows, int* __restrict__ counts, int E){
    for (int i = blockIdx.x * blockDim.x + threadIdx.x; i < E; i += gridDim.x * blockDim.x)
        atomicAdd(&counts[rows[i]], 1);
}

__global__ __launch_bounds__(1024) void scan_partial(const int* __restrict__ counts,
                                                     int* __restrict__ cursor,
                                                     int* __restrict__ tops, int n)
{
    __shared__ int wsum[16];
    const int tid = threadIdx.x, lane = tid & 63, wv = tid >> 6;
    int i = blockIdx.x * 1024 + tid;
    int x = (i < n) ? counts[i] : 0;
    int inc = x;
    #pragma unroll
    for (int d = 1; d < 64; d <<= 1){
        int t = __shfl_up(inc, d);
        if (lane >= d) inc += t;
    }
    if (lane == 63) wsum[wv] = inc;
    __syncthreads();
    if (tid < 16){
        int s = wsum[tid], si = s;
        #pragma unroll
        for (int d = 1; d < 16; d <<= 1){
            int t = __shfl_up(si, d);
            if (tid >= d) si += t;
        }
        wsum[tid] = si - s;
    }
    __syncthreads();
    int excl = inc - x + wsum[wv];
    if (i < n) cursor[i] = excl;
    if (tid == 1023) tops[blockIdx.x] = wsum[15] + inc;
}

__global__ __launch_bounds__(1024) void scan_tops(int* __restrict__ tops, int nb){
    __shared__ int wsum[16];
    const int tid = threadIdx.x, lane = tid & 63, wv = tid >> 6;
    int x = (tid < nb) ? tops[tid] : 0;
    int inc = x;
    #pragma unroll
    for (int d = 1; d < 64; d <<= 1){
        int t = __shfl_up(inc, d);
        if (lane >= d) inc += t;
    }
    if (lane == 63) wsum[wv] = inc;
    __syncthreads();
    if (tid < 16){
        int s = wsum[tid], si = s;
        #pragma unroll
        for (int d = 1; d < 16; d <<= 1){
            int t = __shfl_up(si, d);
            if (tid >= d) si += t;
        }
        wsum[tid] = si - s;
    }
    __syncthreads();
    if (tid < nb) tops[tid] = inc - x + wsum[wv];
}

__global__ __launch_bounds__(1024) void scan_add(int* __restrict__ cursor,
                                                 const int* __restrict__ tops, int n){
    int i = blockIdx.x * 1024 + threadIdx.x;
    if (i < n) cursor[i] += tops[blockIdx.x];
}

// 8-byte record: x = row | (col<<16), y = bf16(ef0) | (bf16(ef1)<<16)
__global__ void pack_kernel(const int* __restrict__ rows, const int* __restrict__ cols,
                            const float* __restrict__ EF, int* __restrict__ cursor,
                            uint2* __restrict__ erec, int E){
    for (int i = blockIdx.x * blockDim.x + threadIdx.x; i < E; i += gridDim.x * blockDim.x){
        int r = rows[i];
        int pos = atomicAdd(&cursor[r], 1);
        float2 ef = *(const float2*)&EF[2 * i];
        uint2 v;
        v.x = (unsigned)r | ((unsigned)cols[i] << 16);
        v.y = (unsigned)f2bf(ef.x) | ((unsigned)f2bf(ef.y) << 16);
        erec[pos] = v;
    }
}

__global__ void pad_kernel(uint2* __restrict__ erec, int E, int Epad){
    int i = E + blockIdx.x * blockDim.x + threadIdx.x;
    if (i < Epad){ uint2 v; v.x = 0xFFFFu; v.y = 0u; erec[i] = v; }
}

// issue U/V gathers for a record (loads start here; waited at first use)
#define ISSUE_UV(recv, U0, U1, V0, V1) do {                                  \
    int rr_ = (int)((recv).x & 0xFFFFu); if (rr_ == 0xFFFF) rr_ = 0;         \
    int cc_ = (int)((recv).x >> 16);                                         \
    const u16* pu_ = Ubf + (size_t)rr_ * 64 + quad * 8;                      \
    const u16* pv_ = Vbf + (size_t)cc_ * 64 + quad * 8;                      \
    U0 = *(const bf16x8*)(pu_);                                              \
    U1 = *(const bf16x8*)(pu_ + 32);                                         \
    V0 = *(const bf16x8*)(pv_);                                              \
    V1 = *(const bf16x8*)(pv_ + 32);                                         \
} while (0)

// ---------------- message: hid = relu(U[r]+V[c]+ef·W1c); msg = hid@W2+b2 -----
__global__ __launch_bounds__(256, 3) void msg_kernel(
    const u16* __restrict__ Ubf, const u16* __restrict__ Vbf,
    const uint2* __restrict__ erec,
    const float* __restrict__ W1,   // [130][64] of this layer (ef rows 128,129)
    const float* __restrict__ W2, const float* __restrict__ B2,
    float* __restrict__ agg, int ntiles, int ipb)
{
    __shared__ float sMsg[4][16 * 68];
    const int tid = threadIdx.x;
    const int w = tid >> 6, l = tid & 63, l15 = l & 15, quad = l >> 4;
    const int w16 = w * 16;

    bf16x8 bW2[2][4];
    #pragma unroll
    for (int kk = 0; kk < 2; ++kk)
        #pragma unroll
        for (int f = 0; f < 4; ++f)
            bW2[kk][f] = load_bfrag(W2, 64, f * 16 + l15, kk * 32 + quad * 8);
    float bias2[4];
    #pragma unroll
    for (int f = 0; f < 4; ++f) bias2[f] = B2[f * 16 + l15];

    // per-lane ef-row weights at k = quad*8+j (lo) and 32+quad*8+j (hi)
    const float* Wc0 = W1 + 128 * 64;
    const float* Wc1 = W1 + 129 * 64;
    float e0l[8], e0h[8], e1l[8], e1h[8];
    #pragma unroll
    for (int j = 0; j < 8; ++j){
        int kl = quad * 8 + j;
        e0l[j] = Wc0[kl];       e0h[j] = Wc0[32 + kl];
        e1l[j] = Wc1[kl];       e1h[j] = Wc1[32 + kl];
    }

    float* myMsg = sMsg[w];

    int tstart = blockIdx.x * ipb;
    int tend = tstart + ipb; if (tend > ntiles) tend = ntiles;
    if (tstart >= tend) return;

    // 2-deep pipeline: rec two ahead, U/V gathers one ahead
    uint2 recA = erec[(size_t)tstart * 64 + w16 + l15];
    uint2 recB = (tstart + 1 < tend) ? erec[(size_t)(tstart + 1) * 64 + w16 + l15] : recA;
    bf16x8 u0, u1, v0, v1;
    ISSUE_UV(recA, u0, u1, v0, v1);

    for (int t = tstart; t < tend; ++t){
        int tpre = t + 2 < tend ? t + 2 : tend - 1;
        uint2 recC = erec[(size_t)tpre * 64 + w16 + l15];
        bf16x8 nu0, nu1, nv0, nv1;
        ISSUE_UV(recB, nu0, nu1, nv0, nv1);      // next tile's gathers in flight

        // decode current record
        int rn_raw = (int)(recA.x & 0xFFFFu);
        int rn = (rn_raw == 0xFFFF) ? -1 : rn_raw;
        float ef0 = bf2f((short)(recA.y & 0xFFFFu));
        float ef1 = bf2f((short)(recA.y >> 16));

        // independent ef contribution while gathers complete
        float hA[8], hB[8];
        #pragma unroll
        for (int j = 0; j < 8; ++j){
            hA[j] = fmaf(ef1, e1l[j], ef0 * e0l[j]);
            hB[j] = fmaf(ef1, e1h[j], ef0 * e0h[j]);
        }

        bf16x8 a0, a1;
        #pragma unroll
        for (int j = 0; j < 8; ++j){
            float xl = hA[j] + bf2f(u0[j]) + bf2f(v0[j]);
            float xh = hB[j] + bf2f(u1[j]) + bf2f(v1[j]);
            a0[j] = (short)f2bf(xl > 0.f ? xl : 0.f);
            a1[j] = (short)f2bf(xh > 0.f ? xh : 0.f);
        }

        f32x4 m[4];
        #pragma unroll
        for (int f = 0; f < 4; ++f){ m[f][0]=bias2[f]; m[f][1]=bias2[f]; m[f][2]=bias2[f]; m[f][3]=bias2[f]; }
        #pragma unroll
        for (int f = 0; f < 4; ++f) m[f] = MFMA16(a0, bW2[0][f], m[f]);
        #pragma unroll
        for (int f = 0; f < 4; ++f) m[f] = MFMA16(a1, bW2[1][f], m[f]);

        // C-layout messages -> LDS so lane = feature
        #pragma unroll
        for (int f = 0; f < 4; ++f)
            #pragma unroll
            for (int r = 0; r < 4; ++r)
                myMsg[(quad * 4 + r) * 68 + f * 16 + l15] = m[f][r];

        // segmented reduction over 16 row-sorted edges
        float accv = 0.f;
        int cur = __shfl(rn, 0);
        #pragma unroll
        for (int j = 0; j < 16; ++j){
            int rj = __shfl(rn, j);
            if (rj != cur){
                if (cur >= 0) atomicAdd(agg + (size_t)cur * 64 + l, accv);
                accv = 0.f; cur = rj;
            }
            accv += myMsg[j * 68 + l];
        }
        if (cur >= 0) atomicAdd(agg + (size_t)cur * 64 + l, accv);

        // rotate pipeline
        recA = recB; recB = recC;
        u0 = nu0; u1 = nu1; v0 = nv0; v1 = nv1;
    }
}

// ------- update: h = relu(LN(agg + h@SW + SB)); zero agg; emit U,V next -----
__global__ __launch_bounds__(256) void update_kernel(
    u16* __restrict__ hbf, float* __restrict__ agg,
    const float* __restrict__ SW, const float* __restrict__ SB,
    const float* __restrict__ LG, const float* __restrict__ LB,
    const float* __restrict__ cW1, const float* __restrict__ cB1,  // next layer (may be null)
    u16* __restrict__ Ubf, u16* __restrict__ Vbf, int N)
{
    __shared__ u16 sH[64 * 72];
    const int tid = threadIdx.x;
    const int w = tid >> 6, l = tid & 63, l15 = l & 15, quad = l >> 4;

    bf16x8 bW[2][4];
    #pragma unroll
    for (int kk = 0; kk < 2; ++kk)
        #pragma unroll
        for (int f = 0; f < 4; ++f)
            bW[kk][f] = load_bfrag(SW, 64, f * 16 + l15, kk * 32 + quad * 8);
    float sb[4], lg[4], lb[4];
    #pragma unroll
    for (int f = 0; f < 4; ++f){
        int n = f * 16 + l15;
        sb[f] = SB[n]; lg[f] = LG[n]; lb[f] = LB[n];
    }

    const int nbase = blockIdx.x * 64 + w * 16;
    int na = nbase + l15; if (na > N - 1) na = N - 1;
    const u16* pa = hbf + (size_t)na * 64 + quad * 8;
    bf16x8 h0 = *(const bf16x8*)pa;
    bf16x8 h1 = *(const bf16x8*)(pa + 32);

    f32x4 acc[4] = {};
    #pragma unroll
    for (int f = 0; f < 4; ++f) acc[f] = MFMA16(h0, bW[0][f], acc[f]);
    #pragma unroll
    for (int f = 0; f < 4; ++f) acc[f] = MFMA16(h1, bW[1][f], acc[f]);

    float vals[4][4];
    #pragma unroll
    for (int r = 0; r < 4; ++r){
        int node = nbase + quad * 4 + r; if (node > N - 1) node = N - 1;
        #pragma unroll
        for (int f = 0; f < 4; ++f)
            vals[f][r] = acc[f][r] + sb[f] + agg[(size_t)node * 64 + f * 16 + l15];
    }

    #pragma unroll
    for (int r = 0; r < 4; ++r){
        float s  = vals[0][r] + vals[1][r] + vals[2][r] + vals[3][r];
        float sq = vals[0][r]*vals[0][r] + vals[1][r]*vals[1][r]
                 + vals[2][r]*vals[2][r] + vals[3][r]*vals[3][r];
        #pragma unroll
        for (int msk = 1; msk < 16; msk <<= 1){
            s  += __shfl_xor(s,  msk);
            sq += __shfl_xor(sq, msk);
        }
        float mean = s * (1.f / 64.f);
        float var  = sq * (1.f / 64.f) - mean * mean;
        float rstd = rsqrtf(var + 1e-5f);
        int node = nbase + quad * 4 + r;
        #pragma unroll
        for (int f = 0; f < 4; ++f){
            float hv = (vals[f][r] - mean) * rstd * lg[f] + lb[f];
            hv = hv > 0.f ? hv : 0.f;
            u16 hb = f2bf(hv);
            sH[(w * 16 + quad * 4 + r) * 72 + f * 16 + l15] = hb;
            if (node < N){
                hbf[(size_t)node * 64 + f * 16 + l15] = hb;
                agg[(size_t)node * 64 + f * 16 + l15] = 0.f;   // ready for next layer
            }
        }
    }

    if (cW1){
        bf16x8 bA[2][4], bB[2][4];
        #pragma unroll
        for (int kk = 0; kk < 2; ++kk)
            #pragma unroll
            for (int f = 0; f < 4; ++f){
                int n = f * 16 + l15, k0 = kk * 32 + quad * 8;
                bA[kk][f] = load_bfrag(cW1,           64, n, k0);
                bB[kk][f] = load_bfrag(cW1 + 64 * 64, 64, n, k0);
            }
        float b1n[4];
        #pragma unroll
        for (int f = 0; f < 4; ++f) b1n[f] = cB1[f * 16 + l15];

        bf16x8 a0 = *(const bf16x8*)&sH[(w * 16 + l15) * 72 + quad * 8];
        bf16x8 a1 = *(const bf16x8*)&sH[(w * 16 + l15) * 72 + 32 + quad * 8];

        f32x4 ua[4], va[4];
        #pragma unroll
        for (int f = 0; f < 4; ++f){
            ua[f][0]=b1n[f]; ua[f][1]=b1n[f]; ua[f][2]=b1n[f]; ua[f][3]=b1n[f];
            va[f][0]=0.f; va[f][1]=0.f; va[f][2]=0.f; va[f][3]=0.f;
        }
        #pragma unroll
        for (int f = 0; f < 4; ++f){ ua[f] = MFMA16(a0, bA[0][f], ua[f]); va[f] = MFMA16(a0, bB[0][f], va[f]); }
        #pragma unroll
        for (int f = 0; f < 4; ++f){ ua[f] = MFMA16(a1, bA[1][f], ua[f]); va[f] = MFMA16(a1, bB[1][f], va[f]); }

        #pragma unroll
        for (int r = 0; r < 4; ++r){
            int node = nbase + quad * 4 + r;
            if (node < N){
                #pragma unroll
                for (int f = 0; f < 4; ++f){
                    Ubf[(size_t)node * 64 + f * 16 + l15] = f2bf(ua[f][r]);
                    Vbf[(size_t)node * 64 + f * 16 + l15] = f2bf(va[f][r]);
                }
            }
        }
    }
}

// ---------------- head: out = relu(h@W1+b1)@W2 + b2  [N][8] f32 --------------
__global__ __launch_bounds__(256) void head_kernel(
    const u16* __restrict__ hbf,
    const float* __restrict__ W1, const float* __restrict__ B1,
    const float* __restrict__ W2, const float* __restrict__ B2,
    float* __restrict__ out, int N)
{
    __shared__ u16 sT[64 * 72];
    const int tid = threadIdx.x;
    const int w = tid >> 6, l = tid & 63, l15 = l & 15, quad = l >> 4;

    bf16x8 bW1[2][4];
    #pragma unroll
    for (int kk = 0; kk < 2; ++kk)
        #pragma unroll
        for (int f = 0; f < 4; ++f)
            bW1[kk][f] = load_bfrag(W1, 64, f * 16 + l15, kk * 32 + quad * 8);
    float b1v[4];
    #pragma unroll
    for (int f = 0; f < 4; ++f) b1v[f] = B1[f * 16 + l15];

    bf16x8 bW2[2];
    #pragma unroll
    for (int kk = 0; kk < 2; ++kk)
        #pragma unroll
        for (int j = 0; j < 8; ++j){
            int k = kk * 32 + quad * 8 + j;
            bW2[kk][j] = (l15 < 8) ? (short)f2bf(W2[k * 8 + l15]) : (short)0;
        }
    float b2v = (l15 < 8) ? B2[l15] : 0.f;

    const int nbase = blockIdx.x * 64 + w * 16;
    int na = nbase + l15; if (na > N - 1) na = N - 1;
    const u16* pa = hbf + (size_t)na * 64 + quad * 8;
    bf16x8 a0 = *(const bf16x8*)pa;
    bf16x8 a1 = *(const bf16x8*)(pa + 32);

    f32x4 acc[4];
    #pragma unroll
    for (int f = 0; f < 4; ++f){ acc[f][0]=b1v[f]; acc[f][1]=b1v[f]; acc[f][2]=b1v[f]; acc[f][3]=b1v[f]; }
    #pragma unroll
    for (int f = 0; f < 4; ++f) acc[f] = MFMA16(a0, bW1[0][f], acc[f]);
    #pragma unroll
    for (int f = 0; f < 4; ++f) acc[f] = MFMA16(a1, bW1[1][f], acc[f]);

    u16* myT = sT + (w * 16) * 72;
    #pragma unroll
    for (int f = 0; f < 4; ++f)
        #pragma unroll
        for (int r = 0; r < 4; ++r){
            float v = acc[f][r] > 0.f ? acc[f][r] : 0.f;
            myT[(quad * 4 + r) * 72 + f * 16 + l15] = f2bf(v);
        }

    f32x4 o = { b2v, b2v, b2v, b2v };
    #pragma unroll
    for (int kk = 0; kk < 2; ++kk){
        bf16x8 a = *(const bf16x8*)&myT[l15 * 72 + kk * 32 + quad * 8];
        o = MFMA16(a, bW2[kk], o);
    }
    #pragma unroll
    for (int r = 0; r < 4; ++r){
        int node = nbase + quad * 4 + r;
        if (node < N && l15 < 8)
            out[(size_t)node * 8 + l15] = o[r];
    }
}

extern "C" void kernel_launch(void* const* d_in, const int* in_sizes, int n_in,
                              void* d_out, int out_size, void* d_ws, size_t ws_size,
                              hipStream_t stream)
{
    const float* X      = (const float*)d_in[0];
    const int*   EI     = (const int*)d_in[1];
    const float* EF     = (const float*)d_in[2];
    const float* encW1  = (const float*)d_in[4];
    const float* encB1  = (const float*)d_in[5];
    const float* encW2  = (const float*)d_in[6];
    const float* encB2  = (const float*)d_in[7];
    const float* convW1 = (const float*)d_in[8];
    const float* convB1 = (const float*)d_in[9];
    const float* convW2 = (const float*)d_in[10];
    const float* convB2 = (const float*)d_in[11];
    const float* skipW  = (const float*)d_in[12];
    const float* skipB  = (const float*)d_in[13];
    const float* lnG    = (const float*)d_in[14];
    const float* lnB    = (const float*)d_in[15];
    const float* headW1 = (const float*)d_in[16];
    const float* headB1 = (const float*)d_in[17];
    const float* headW2 = (const float*)d_in[18];
    const float* headB2 = (const float*)d_in[19];

    const int N = in_sizes[0] / 3;      // NOTE: record packing assumes N < 65535
    const int E = in_sizes[1] / 2;
    const int L = in_sizes[8] / (130 * 64);
    const int* rows = EI;
    const int* cols = EI + E;

    const int ntilesN = (N + 63) / 64;
    const int ntilesE = (E + 63) / 64;
    const int Epad = ntilesE * 64;

    auto align256 = [](size_t x){ return (x + 255) & ~(size_t)255; };
    char* p = (char*)d_ws;
    u16* hbf = (u16*)p;             p += align256((size_t)N * 64 * 2);
    u16* Ubf = (u16*)p;             p += align256((size_t)N * 64 * 2);
    u16* Vbf = (u16*)p;             p += align256((size_t)N * 64 * 2);
    float* agg = (float*)p;         p += align256((size_t)N * 64 * 4);
    uint2* erec = (uint2*)p;        p += align256((size_t)Epad * 8);
    int* counts = (int*)p;          p += align256((size_t)N * 4);
    int* cursor = (int*)p;          p += align256((size_t)N * 4);
    int* tops = (int*)p;            p += align256(4096);

    const int nblkS = (N + 1023) / 1024;

    // ---- build sorted packed edge records (once per call) ----
    hipMemsetAsync(counts, 0, (size_t)N * sizeof(int), stream);
    count_kernel<<<1280, 256, 0, stream>>>(rows, counts, E);
    scan_partial<<<nblkS, 1024, 0, stream>>>(counts, cursor, tops, N);
    scan_tops<<<1, 1024, 0, stream>>>(tops, nblkS);
    scan_add<<<nblkS, 1024, 0, stream>>>(cursor, tops, N);
    pack_kernel<<<1280, 256, 0, stream>>>(rows, cols, EF, cursor, erec, E);
    if (Epad > E)
        pad_kernel<<<(Epad - E + 255) / 256, 256, 0, stream>>>(erec, E, Epad);

    hipMemsetAsync(agg, 0, (size_t)N * 64 * sizeof(float), stream);
    enc_kernel<<<ntilesN, 256, 0, stream>>>(X, encW1, encB1, encW2, encB2,
                                            convW1, convB1, hbf, Ubf, Vbf, N);

    const int msg_blocks = ntilesE < 2048 ? ntilesE : 2048;
    const int ipb = (ntilesE + msg_blocks - 1) / msg_blocks;

    for (int li = 0; li < L; ++li){
        msg_kernel<<<msg_blocks, 256, 0, stream>>>(Ubf, Vbf, erec,
            convW1 + (size_t)li * 130 * 64,
            convW2 + (size_t)li * 64 * 64, convB2 + li * 64,
            agg, ntilesE, ipb);
        const float* w1n = (li + 1 < L) ? convW1 + (size_t)(li + 1) * 130 * 64 : nullptr;
        const float* b1n = (li + 1 < L) ? convB1 + (li + 1) * 64 : nullptr;
        update_kernel<<<ntilesN, 256, 0, stream>>>(hbf, agg,
            skipW + (size_t)li * 64 * 64, skipB + li * 64,
            lnG + li * 64, lnB + li * 64, w1n, b1n, Ubf, Vbf, N);
    }
    head_kernel<<<ntilesN, 256, 0, stream>>>(hbf, headW1, headB1, headW2, headB2,
                                             (float*)d_out, N);
}